// Round 1
// baseline (1837.665 us; speedup 1.0000x reference)
//
#include <hip/hip_runtime.h>

#define D_MODEL 1024
#define NHEADS  16
#define DK      64
#define SEQ     2048
#define NBATCH  2
#define MTOT    (NBATCH * SEQ)   // 4096 rows

// ---------------------------------------------------------------------------
// GEMM (NT + bias): C[M,N] = A[M,K] @ W[N,K]^T + bias[N]   (torch Linear)
// 64x64 tile, BK=16, 256 threads, 4x4 micro-tile.
// LDS stored transposed As[k][m] with row stride 68 (16B-aligned rows,
// compute-phase float4 reads are 2-way bank aliased = free).
// ---------------------------------------------------------------------------
__global__ __launch_bounds__(256) void gemm_nt_bias_f32(
    const float* __restrict__ A, const float* __restrict__ W,
    const float* __restrict__ bias, float* __restrict__ C,
    int K, int N)
{
    __shared__ float As[16][68];
    __shared__ float Bs[16][68];

    const int t  = threadIdx.x;
    const int m0 = blockIdx.y * 64;
    const int n0 = blockIdx.x * 64;
    const int tr = t >> 4;        // 0..15  (micro-tile row group)
    const int tc = t & 15;        // 0..15  (micro-tile col group)
    const int lr = t >> 2;        // 0..63  (load row)
    const int lk = (t & 3) * 4;   // 0,4,8,12 (load k offset)

    float acc[4][4];
#pragma unroll
    for (int i = 0; i < 4; ++i)
#pragma unroll
        for (int j = 0; j < 4; ++j) acc[i][j] = 0.f;

    const float* Ap = &A[(size_t)(m0 + lr) * K + lk];
    const float* Wp = &W[(size_t)(n0 + lr) * K + lk];

    for (int k0 = 0; k0 < K; k0 += 16) {
        float4 a = *(const float4*)(Ap + k0);
        float4 w = *(const float4*)(Wp + k0);
        As[lk + 0][lr] = a.x; As[lk + 1][lr] = a.y;
        As[lk + 2][lr] = a.z; As[lk + 3][lr] = a.w;
        Bs[lk + 0][lr] = w.x; Bs[lk + 1][lr] = w.y;
        Bs[lk + 2][lr] = w.z; Bs[lk + 3][lr] = w.w;
        __syncthreads();
#pragma unroll
        for (int kk = 0; kk < 16; ++kk) {
            float4 av4 = *(const float4*)&As[kk][tr * 4];
            float4 bv4 = *(const float4*)&Bs[kk][tc * 4];
            float av[4] = {av4.x, av4.y, av4.z, av4.w};
            float bv[4] = {bv4.x, bv4.y, bv4.z, bv4.w};
#pragma unroll
            for (int i = 0; i < 4; ++i)
#pragma unroll
                for (int j = 0; j < 4; ++j)
                    acc[i][j] += av[i] * bv[j];
        }
        __syncthreads();
    }

    float4 b4 = *(const float4*)&bias[n0 + tc * 4];
#pragma unroll
    for (int i = 0; i < 4; ++i) {
        float4 o;
        o.x = acc[i][0] + b4.x;
        o.y = acc[i][1] + b4.y;
        o.z = acc[i][2] + b4.z;
        o.w = acc[i][3] + b4.w;
        *(float4*)&C[(size_t)(m0 + tr * 4 + i) * N + n0 + tc * 4] = o;
    }
}

// ---------------------------------------------------------------------------
// Flash-style MHA: one block per (batch, head, 64-row Q tile).
// 256 threads: thread t -> q-row (t>>2), column-quarter c = t&3 (16 cols).
// Online softmax; P written into K's LDS buffer after a barrier (producers
// and consumers of a given row share a wave -> no extra barrier needed).
// LDS: 3 * 64*68*4 = 51 KB.
// ---------------------------------------------------------------------------
__global__ __launch_bounds__(256) void mha_flash_f32(
    const float* __restrict__ Qg, const float* __restrict__ Kg,
    const float* __restrict__ Vg, float* __restrict__ Og)
{
    __shared__ float Qs[64][68];
    __shared__ float KPs[64][68];   // K tile, then re-used for P
    __shared__ float Vs[64][68];

    const int t  = threadIdx.x;
    const int bx = blockIdx.x;
    const int qt = bx & 31;          // S/64 = 32 q-tiles
    const int h  = (bx >> 5) & 15;
    const int b  = bx >> 9;
    const int q0 = qt * 64;

    const int q = t >> 2;            // 0..63 q-row in tile
    const int c = t & 3;             // column quarter

    // ---- load Q tile (coalesced float4) ----
#pragma unroll
    for (int i = 0; i < 4; ++i) {
        int e  = t + i * 256;        // 0..1023 float4 slots
        int r  = e >> 4;
        int c4 = (e & 15) * 4;
        float4 v = *(const float4*)&Qg[(size_t)(b * SEQ + q0 + r) * D_MODEL + h * DK + c4];
        *(float4*)&Qs[r][c4] = v;    // 68r + c4 is 16B aligned
    }

    float O[16];
#pragma unroll
    for (int i = 0; i < 16; ++i) O[i] = 0.f;
    float m_run = -1e30f, l_run = 0.f;

    for (int kt = 0; kt < SEQ / 64; ++kt) {
        const int kv0 = kt * 64;
#pragma unroll
        for (int i = 0; i < 4; ++i) {
            int e  = t + i * 256;
            int r  = e >> 4;
            int c4 = (e & 15) * 4;
            size_t row = (size_t)(b * SEQ + kv0 + r) * D_MODEL + h * DK + c4;
            *(float4*)&KPs[r][c4] = *(const float4*)&Kg[row];
            *(float4*)&Vs[r][c4]  = *(const float4*)&Vg[row];
        }
        __syncthreads();   // K/V tile visible (also covers Qs on iter 0)

        // ---- S = Q K^T / sqrt(dk) for 16 columns of this thread ----
        float s[16];
#pragma unroll
        for (int jj = 0; jj < 16; ++jj) s[jj] = 0.f;
#pragma unroll 4
        for (int d0 = 0; d0 < DK; d0 += 4) {
            float4 qv = *(const float4*)&Qs[q][d0];
#pragma unroll
            for (int jj = 0; jj < 16; ++jj) {
                float4 kv = *(const float4*)&KPs[c * 16 + jj][d0];
                s[jj] += qv.x * kv.x + qv.y * kv.y + qv.z * kv.z + qv.w * kv.w;
            }
        }
        float mt = -1e30f;
#pragma unroll
        for (int jj = 0; jj < 16; ++jj) {
            s[jj] *= 0.125f;               // 1/sqrt(64)
            mt = fmaxf(mt, s[jj]);
        }
        // row reduction across the 4 sibling lanes (same wave)
        mt = fmaxf(mt, __shfl_xor(mt, 1));
        mt = fmaxf(mt, __shfl_xor(mt, 2));
        float m_new = fmaxf(m_run, mt);
        float alpha = __expf(m_run - m_new);   // exp(-1e30) == 0 on first tile
        float rs = 0.f;
#pragma unroll
        for (int jj = 0; jj < 16; ++jj) {
            s[jj] = __expf(s[jj] - m_new);
            rs += s[jj];
        }
        rs += __shfl_xor(rs, 1);
        rs += __shfl_xor(rs, 2);
        l_run = l_run * alpha + rs;
        m_run = m_new;
#pragma unroll
        for (int i = 0; i < 16; ++i) O[i] *= alpha;

        __syncthreads();   // everyone done reading K tile before P overwrites
#pragma unroll
        for (int jj = 0; jj < 16; ++jj) KPs[q][c * 16 + jj] = s[jj];
        // P rows are written and read by the same wave -> no barrier needed

        // ---- O += P V ----
        for (int j = 0; j < 64; ++j) {
            float p = KPs[q][j];
#pragma unroll
            for (int d4 = 0; d4 < 4; ++d4) {
                float4 v = *(const float4*)&Vs[j][c * 16 + d4 * 4];
                O[d4 * 4 + 0] += p * v.x;
                O[d4 * 4 + 1] += p * v.y;
                O[d4 * 4 + 2] += p * v.z;
                O[d4 * 4 + 3] += p * v.w;
            }
        }
        __syncthreads();   // before next tile load overwrites KPs/Vs
    }

    const float inv = 1.f / l_run;
    const size_t orow = (size_t)(b * SEQ + q0 + q) * D_MODEL + h * DK + c * 16;
#pragma unroll
    for (int d4 = 0; d4 < 4; ++d4) {
        float4 o;
        o.x = O[d4 * 4 + 0] * inv;
        o.y = O[d4 * 4 + 1] * inv;
        o.z = O[d4 * 4 + 2] * inv;
        o.w = O[d4 * 4 + 3] * inv;
        *(float4*)&Og[orow + d4 * 4] = o;
    }
}

// ---------------------------------------------------------------------------
extern "C" void kernel_launch(void* const* d_in, const int* in_sizes, int n_in,
                              void* d_out, int out_size, void* d_ws, size_t ws_size,
                              hipStream_t stream)
{
    const float* query = (const float*)d_in[0];
    const float* key   = (const float*)d_in[1];
    const float* value = (const float*)d_in[2];
    const float* Wq    = (const float*)d_in[3];
    const float* bq    = (const float*)d_in[4];
    const float* Wk    = (const float*)d_in[5];
    const float* bk    = (const float*)d_in[6];
    const float* Wv    = (const float*)d_in[7];
    const float* bv    = (const float*)d_in[8];
    const float* Wo    = (const float*)d_in[9];
    const float* bo    = (const float*)d_in[10];
    float* out = (float*)d_out;

    // workspace: Q,K,V,attn-out, 16 MB each (64 MB total), fully rewritten
    float* Q  = (float*)d_ws;
    float* K  = Q + (size_t)MTOT * D_MODEL;
    float* V  = K + (size_t)MTOT * D_MODEL;
    float* AT = V + (size_t)MTOT * D_MODEL;

    dim3 ggrid(D_MODEL / 64, MTOT / 64);   // (16, 64) = 1024 blocks

    gemm_nt_bias_f32<<<ggrid, 256, 0, stream>>>(query, Wq, bq, Q, D_MODEL, D_MODEL);
    gemm_nt_bias_f32<<<ggrid, 256, 0, stream>>>(key,   Wk, bk, K, D_MODEL, D_MODEL);
    gemm_nt_bias_f32<<<ggrid, 256, 0, stream>>>(value, Wv, bv, V, D_MODEL, D_MODEL);

    mha_flash_f32<<<NBATCH * NHEADS * (SEQ / 64), 256, 0, stream>>>(Q, K, V, AT);

    gemm_nt_bias_f32<<<ggrid, 256, 0, stream>>>(AT, Wo, bo, out, D_MODEL, D_MODEL);
}

// Round 2
// 704.952 us; speedup vs baseline: 2.6068x; 2.6068x over previous
//
#include <hip/hip_runtime.h>

#define D_MODEL 1024
#define NHEADS  16
#define DK      64
#define SEQ     2048
#define NBATCH  2
#define MTOT    (NBATCH * SEQ)   // 4096 rows

typedef _Float16 f16;
typedef _Float16 f16x4 __attribute__((ext_vector_type(4)));
typedef _Float16 f16x8 __attribute__((ext_vector_type(8)));
typedef float    f32x4 __attribute__((ext_vector_type(4)));

// ---------------------------------------------------------------------------
// GEMM (NT + bias): C[M,N] = A[M,K] @ W[N,K]^T + bias[N], M=4096, N=K=1024.
// 64x64 tile, BK=16, 256 threads, 4x4 micro-tile. Epilogue modes:
//   MODE 0: fp32 natural   (final output)
//   MODE 1: fp16 natural   (Q, K for attention)
//   MODE 2: fp16 transposed Vt[(b*16+h)*64+d][s]  (V for attention)
// ---------------------------------------------------------------------------
template<int MODE>
__global__ __launch_bounds__(256) void gemm_nt_bias(
    const float* __restrict__ A, const float* __restrict__ W,
    const float* __restrict__ bias, void* __restrict__ Cout)
{
    __shared__ float As[16][68];
    __shared__ float Bs[16][68];

    const int t  = threadIdx.x;
    const int m0 = blockIdx.y * 64;
    const int n0 = blockIdx.x * 64;
    const int tr = t >> 4;
    const int tc = t & 15;
    const int lr = t >> 2;
    const int lk = (t & 3) * 4;

    float acc[4][4];
#pragma unroll
    for (int i = 0; i < 4; ++i)
#pragma unroll
        for (int j = 0; j < 4; ++j) acc[i][j] = 0.f;

    const float* Ap = &A[(size_t)(m0 + lr) * D_MODEL + lk];
    const float* Wp = &W[(size_t)(n0 + lr) * D_MODEL + lk];

    for (int k0 = 0; k0 < D_MODEL; k0 += 16) {
        float4 a = *(const float4*)(Ap + k0);
        float4 w = *(const float4*)(Wp + k0);
        As[lk + 0][lr] = a.x; As[lk + 1][lr] = a.y;
        As[lk + 2][lr] = a.z; As[lk + 3][lr] = a.w;
        Bs[lk + 0][lr] = w.x; Bs[lk + 1][lr] = w.y;
        Bs[lk + 2][lr] = w.z; Bs[lk + 3][lr] = w.w;
        __syncthreads();
#pragma unroll
        for (int kk = 0; kk < 16; ++kk) {
            float4 av4 = *(const float4*)&As[kk][tr * 4];
            float4 bv4 = *(const float4*)&Bs[kk][tc * 4];
            float av[4] = {av4.x, av4.y, av4.z, av4.w};
            float bv[4] = {bv4.x, bv4.y, bv4.z, bv4.w};
#pragma unroll
            for (int i = 0; i < 4; ++i)
#pragma unroll
                for (int j = 0; j < 4; ++j)
                    acc[i][j] += av[i] * bv[j];
        }
        __syncthreads();
    }

    float4 b4 = *(const float4*)&bias[n0 + tc * 4];
    float bb4[4] = {b4.x, b4.y, b4.z, b4.w};

    if (MODE == 0) {
        float* C = (float*)Cout;
#pragma unroll
        for (int i = 0; i < 4; ++i) {
            float4 o;
            o.x = acc[i][0] + bb4[0];
            o.y = acc[i][1] + bb4[1];
            o.z = acc[i][2] + bb4[2];
            o.w = acc[i][3] + bb4[3];
            *(float4*)&C[(size_t)(m0 + tr * 4 + i) * D_MODEL + n0 + tc * 4] = o;
        }
    } else if (MODE == 1) {
        f16* C = (f16*)Cout;
#pragma unroll
        for (int i = 0; i < 4; ++i) {
            f16x4 o = { (f16)(acc[i][0] + bb4[0]), (f16)(acc[i][1] + bb4[1]),
                        (f16)(acc[i][2] + bb4[2]), (f16)(acc[i][3] + bb4[3]) };
            *(f16x4*)&C[(size_t)(m0 + tr * 4 + i) * D_MODEL + n0 + tc * 4] = o;
        }
    } else {
        // Vt[(b*16+h)*64 + d][s], fp16.  Tile spans one h (n-range 64) and one b.
        f16* Vt = (f16*)Cout;
        const int hh = n0 >> 6;
        const int bb = m0 >> 11;           // m0 / SEQ
        const int s0 = (m0 & (SEQ - 1)) + tr * 4;
#pragma unroll
        for (int j = 0; j < 4; ++j) {
            const int d = tc * 4 + j;
            f16x4 v = { (f16)(acc[0][j] + bb4[j]), (f16)(acc[1][j] + bb4[j]),
                        (f16)(acc[2][j] + bb4[j]), (f16)(acc[3][j] + bb4[j]) };
            *(f16x4*)&Vt[(size_t)((bb * NHEADS + hh) * DK + d) * SEQ + s0] = v;
        }
    }
}

// ---------------------------------------------------------------------------
// MFMA fp16 flash attention. Block = (q-tile 64) x (b,h). 256 thr = 4 waves,
// wave w owns q-rows w*16..w*16+15. 64-key tiles, online softmax in regs.
// mfma_f32_16x16x32_f16:  C/D: col=lane&15, row=quad*4+reg (m89)
//                         A:   A[m=lane&15][k=quad*8+j]    (m120)
//                         B:   B[k=quad*8+j][n=lane&15]
// LDS rows padded to 72 f16 (144 B): frag reads 2-way bank aliased = free.
// ---------------------------------------------------------------------------
__global__ __launch_bounds__(256) void mha_mfma_f16(
    const f16* __restrict__ Qh, const f16* __restrict__ Kh,
    const f16* __restrict__ Vt, float* __restrict__ Og)
{
    __shared__ __align__(16) f16 Qs[64][72];
    __shared__ __align__(16) f16 Ks[64][72];
    __shared__ __align__(16) f16 Vs[64][72];   // V^T tile: [d][j]
    __shared__ __align__(16) f16 Ps[64][72];

    const int t    = threadIdx.x;
    const int w    = t >> 6;
    const int lane = t & 63;
    const int quad = lane >> 4;
    const int l15  = lane & 15;

    const int qt = blockIdx.x;
    const int bh = blockIdx.y;        // b*16 + h
    const int b  = bh >> 4;
    const int h  = bh & 15;
    const int q0 = qt * 64;

    const int r0 = t >> 3;            // 0..31 staging row
    const int c0 = (t & 7) * 8;       // 0..56 staging col (f16x8)

    // ---- stage Q tile (fp16, coalesced 16B) ----
#pragma unroll
    for (int i = 0; i < 2; ++i) {
        int r = r0 + i * 32;
        *(f16x8*)&Qs[r][c0] =
            *(const f16x8*)&Qh[(size_t)(b * SEQ + q0 + r) * D_MODEL + h * DK + c0];
    }
    __syncthreads();

    const f16x8 aQ0 = *(const f16x8*)&Qs[w * 16 + l15][quad * 8];
    const f16x8 aQ1 = *(const f16x8*)&Qs[w * 16 + l15][32 + quad * 8];

    f32x4 o[4];
#pragma unroll
    for (int f = 0; f < 4; ++f) o[f] = (f32x4){0.f, 0.f, 0.f, 0.f};
    float m_run[4], l_run[4];
#pragma unroll
    for (int r = 0; r < 4; ++r) { m_run[r] = -1e30f; l_run[r] = 0.f; }

    for (int kt = 0; kt < SEQ / 64; ++kt) {
        const int kv0 = kt * 64;
        // ---- stage K tile (natural) and V^T tile ----
#pragma unroll
        for (int i = 0; i < 2; ++i) {
            int r = r0 + i * 32;
            *(f16x8*)&Ks[r][c0] =
                *(const f16x8*)&Kh[(size_t)(b * SEQ + kv0 + r) * D_MODEL + h * DK + c0];
            *(f16x8*)&Vs[r][c0] =
                *(const f16x8*)&Vt[(size_t)(bh * DK + r) * SEQ + kv0 + c0];
        }
        __syncthreads();

        // ---- S = Q K^T (wave strip 16 x 64) ----
        f32x4 s[4];
#pragma unroll
        for (int f = 0; f < 4; ++f) {
            f16x8 b0 = *(const f16x8*)&Ks[f * 16 + l15][quad * 8];
            f16x8 b1 = *(const f16x8*)&Ks[f * 16 + l15][32 + quad * 8];
            f32x4 acc = (f32x4){0.f, 0.f, 0.f, 0.f};
            acc = __builtin_amdgcn_mfma_f32_16x16x32_f16(aQ0, b0, acc, 0, 0, 0);
            acc = __builtin_amdgcn_mfma_f32_16x16x32_f16(aQ1, b1, acc, 0, 0, 0);
            s[f] = acc;
        }

        // ---- online softmax (rows = quad*4+r, cols = lanes&15 x 4 tiles) ----
#pragma unroll
        for (int f = 0; f < 4; ++f)
#pragma unroll
            for (int r = 0; r < 4; ++r) s[f][r] *= 0.125f;   // 1/sqrt(64)

#pragma unroll
        for (int r = 0; r < 4; ++r) {
            float v = fmaxf(fmaxf(s[0][r], s[1][r]), fmaxf(s[2][r], s[3][r]));
            v = fmaxf(v, __shfl_xor(v, 1));
            v = fmaxf(v, __shfl_xor(v, 2));
            v = fmaxf(v, __shfl_xor(v, 4));
            v = fmaxf(v, __shfl_xor(v, 8));
            float mn    = fmaxf(m_run[r], v);
            float alpha = __expf(m_run[r] - mn);   // 0 on first tile
            m_run[r] = mn;
            float rsum = 0.f;
#pragma unroll
            for (int f = 0; f < 4; ++f) {
                float p = __expf(s[f][r] - mn);
                s[f][r] = p;
                rsum += p;
            }
            rsum += __shfl_xor(rsum, 1);
            rsum += __shfl_xor(rsum, 2);
            rsum += __shfl_xor(rsum, 4);
            rsum += __shfl_xor(rsum, 8);
            l_run[r] = l_run[r] * alpha + rsum;
#pragma unroll
            for (int f = 0; f < 4; ++f) o[f][r] *= alpha;
        }

        // ---- P: C-layout regs -> LDS (A-layout readback, same-wave rows) ----
#pragma unroll
        for (int f = 0; f < 4; ++f)
#pragma unroll
            for (int r = 0; r < 4; ++r)
                Ps[w * 16 + quad * 4 + r][f * 16 + l15] = (f16)s[f][r];

        // ---- O += P V ----
        f16x8 aP0 = *(const f16x8*)&Ps[w * 16 + l15][quad * 8];
        f16x8 aP1 = *(const f16x8*)&Ps[w * 16 + l15][32 + quad * 8];
#pragma unroll
        for (int f = 0; f < 4; ++f) {
            f16x8 b0 = *(const f16x8*)&Vs[f * 16 + l15][quad * 8];
            f16x8 b1 = *(const f16x8*)&Vs[f * 16 + l15][32 + quad * 8];
            o[f] = __builtin_amdgcn_mfma_f32_16x16x32_f16(aP0, b0, o[f], 0, 0, 0);
            o[f] = __builtin_amdgcn_mfma_f32_16x16x32_f16(aP1, b1, o[f], 0, 0, 0);
        }
        __syncthreads();   // before restaging Ks/Vs
    }

    // ---- epilogue: O / l -> attn out (fp32 natural [B,S,D_MODEL]) ----
#pragma unroll
    for (int r = 0; r < 4; ++r) {
        const float inv = 1.f / l_run[r];
        const size_t row = (size_t)(b * SEQ + q0 + w * 16 + quad * 4 + r) * D_MODEL + h * DK;
#pragma unroll
        for (int f = 0; f < 4; ++f)
            Og[row + f * 16 + l15] = o[f][r] * inv;
    }
}

// ---------------------------------------------------------------------------
extern "C" void kernel_launch(void* const* d_in, const int* in_sizes, int n_in,
                              void* d_out, int out_size, void* d_ws, size_t ws_size,
                              hipStream_t stream)
{
    const float* query = (const float*)d_in[0];
    const float* key   = (const float*)d_in[1];
    const float* value = (const float*)d_in[2];
    const float* Wq    = (const float*)d_in[3];
    const float* bq    = (const float*)d_in[4];
    const float* Wk    = (const float*)d_in[5];
    const float* bk    = (const float*)d_in[6];
    const float* Wv    = (const float*)d_in[7];
    const float* bv    = (const float*)d_in[8];
    const float* Wo    = (const float*)d_in[9];
    const float* bo    = (const float*)d_in[10];
    float* out = (float*)d_out;

    // workspace: Qh(8MB) Kh(8MB) Vt(8MB) fp16, AT(16MB) fp32  = 40 MB
    f16* Qh = (f16*)d_ws;
    f16* Kh = Qh + (size_t)MTOT * D_MODEL;
    f16* Vt = Kh + (size_t)MTOT * D_MODEL;
    float* AT = (float*)(Vt + (size_t)MTOT * D_MODEL);

    dim3 ggrid(D_MODEL / 64, MTOT / 64);   // (16, 64)

    gemm_nt_bias<1><<<ggrid, 256, 0, stream>>>(query, Wq, bq, Qh);
    gemm_nt_bias<1><<<ggrid, 256, 0, stream>>>(key,   Wk, bk, Kh);
    gemm_nt_bias<2><<<ggrid, 256, 0, stream>>>(value, Wv, bv, Vt);

    mha_mfma_f16<<<dim3(SEQ / 64, NBATCH * NHEADS), 256, 0, stream>>>(Qh, Kh, Vt, AT);

    gemm_nt_bias<0><<<ggrid, 256, 0, stream>>>(AT, Wo, bo, out);
}

// Round 3
// 328.244 us; speedup vs baseline: 5.5985x; 2.1477x over previous
//
#include <hip/hip_runtime.h>

#define D_MODEL 1024
#define NHEADS  16
#define DK      64
#define SEQ     2048
#define NBATCH  2
#define MTOT    (NBATCH * SEQ)   // 4096 rows

typedef _Float16 f16;
typedef _Float16 f16x4 __attribute__((ext_vector_type(4)));
typedef _Float16 f16x8 __attribute__((ext_vector_type(8)));
typedef float    f32x4 __attribute__((ext_vector_type(4)));

// ---------------------------------------------------------------------------
// fp32 -> fp16 convert (inputs + weights), one batched launch.
// ---------------------------------------------------------------------------
__global__ __launch_bounds__(256) void cvt_f32_to_f16(
    const float* __restrict__ q, const float* __restrict__ k, const float* __restrict__ v,
    const float* __restrict__ wq, const float* __restrict__ wk,
    const float* __restrict__ wv, const float* __restrict__ wo,
    f16* __restrict__ qf, f16* __restrict__ kf, f16* __restrict__ vf,
    f16* __restrict__ wqh, f16* __restrict__ wkh, f16* __restrict__ wvh, f16* __restrict__ woh)
{
    const int z = blockIdx.y;
    const float* src; f16* dst; int n4;
    if (z == 0)      { src = q;  dst = qf;  n4 = MTOT * D_MODEL / 4; }
    else if (z == 1) { src = k;  dst = kf;  n4 = MTOT * D_MODEL / 4; }
    else if (z == 2) { src = v;  dst = vf;  n4 = MTOT * D_MODEL / 4; }
    else if (z == 3) { src = wq; dst = wqh; n4 = D_MODEL * D_MODEL / 4; }
    else if (z == 4) { src = wk; dst = wkh; n4 = D_MODEL * D_MODEL / 4; }
    else if (z == 5) { src = wv; dst = wvh; n4 = D_MODEL * D_MODEL / 4; }
    else             { src = wo; dst = woh; n4 = D_MODEL * D_MODEL / 4; }
    for (int i = blockIdx.x * 256 + threadIdx.x; i < n4; i += gridDim.x * 256) {
        float4 t = ((const float4*)src)[i];
        f16x4 o = {(f16)t.x, (f16)t.y, (f16)t.z, (f16)t.w};
        ((f16x4*)dst)[i] = o;
    }
}

// ---------------------------------------------------------------------------
// m97-style fp16 MFMA GEMM core: C[128,128] tile of A[M,K] @ W[N,K]^T.
// 256 thr = 4 waves (2x2), wave = 64x64 = 4x4 mfma_f32_16x16x32_f16.
// Staging: global_load_lds width=16 into chunk layout slot = ko*128 + m
// (16B chunk = 8 f16 along k). Deposit is lane-contiguous (HW constraint);
// frag ds_read_b128 at quad*1024 + row*8 is bank-balanced (8 lanes per
// 4-bank group = 8-cycle minimum, no excess conflict).
// ---------------------------------------------------------------------------
__device__ __forceinline__ void gemm128_core(
    const f16* __restrict__ A, const f16* __restrict__ Wm,
    int m0, int n0, f32x4 (&acc)[4][4])
{
    __shared__ __align__(16) f16 As[4096];   // 8 KB
    __shared__ __align__(16) f16 Bs[4096];   // 8 KB

    const int t    = threadIdx.x;
    const int lane = t & 63;
    const int w    = t >> 6;
    const int quad = lane >> 4, l15 = lane & 15;
    const int wr   = w >> 1,    wc  = w & 1;

    // wave w stages chunks j = 2w, 2w+1 (each instr: 64 lanes x 16 B = 1 KB)
    size_t offA[2], offB[2];
#pragma unroll
    for (int jj = 0; jj < 2; ++jj) {
        int s  = (w * 2 + jj) * 64 + lane;   // slot = ko*128 + m
        int ko = s >> 7, m = s & 127;
        offA[jj] = (size_t)(m0 + m) * D_MODEL + ko * 8;
        offB[jj] = (size_t)(n0 + m) * D_MODEL + ko * 8;
    }
    const int jb = __builtin_amdgcn_readfirstlane(w * 2 * 512);  // f16 offset, SGPR

#pragma unroll
    for (int i = 0; i < 4; ++i)
#pragma unroll
        for (int j = 0; j < 4; ++j) acc[i][j] = (f32x4){0.f, 0.f, 0.f, 0.f};

    auto* ldsA = (__attribute__((address_space(3))) f16*)As;
    auto* ldsB = (__attribute__((address_space(3))) f16*)Bs;

    for (int k0 = 0; k0 < D_MODEL; k0 += 32) {
#pragma unroll
        for (int jj = 0; jj < 2; ++jj) {
            __builtin_amdgcn_global_load_lds(
                (const __attribute__((address_space(1))) void*)(A + offA[jj] + k0),
                (__attribute__((address_space(3))) void*)(ldsA + jb + jj * 512),
                16, 0, 0);
            __builtin_amdgcn_global_load_lds(
                (const __attribute__((address_space(1))) void*)(Wm + offB[jj] + k0),
                (__attribute__((address_space(3))) void*)(ldsB + jb + jj * 512),
                16, 0, 0);
        }
        __syncthreads();   // compiler emits vmcnt(0) drain before s_barrier

        f16x8 af[4], bf[4];
#pragma unroll
        for (int i = 0; i < 4; ++i) {
            af[i] = *(const f16x8*)&As[quad * 1024 + (wr * 64 + i * 16 + l15) * 8];
            bf[i] = *(const f16x8*)&Bs[quad * 1024 + (wc * 64 + i * 16 + l15) * 8];
        }
#pragma unroll
        for (int i = 0; i < 4; ++i)
#pragma unroll
            for (int j = 0; j < 4; ++j)
                acc[i][j] = __builtin_amdgcn_mfma_f32_16x16x32_f16(af[i], bf[j], acc[i][j], 0, 0, 0);
        __syncthreads();   // before next iter's deposits overwrite
    }
}

// Fused Q/K/V projection: grid (8, 32, 3) -> 768 blocks = 3/CU.
__global__ __launch_bounds__(256, 3) void qkv_gemm(
    const f16* __restrict__ Qf, const f16* __restrict__ Kf, const f16* __restrict__ Vf,
    const f16* __restrict__ Wqh, const f16* __restrict__ Wkh, const f16* __restrict__ Wvh,
    const float* __restrict__ bq, const float* __restrict__ bk, const float* __restrict__ bv,
    f16* __restrict__ Qh, f16* __restrict__ Kh, f16* __restrict__ Vt)
{
    const int z = blockIdx.z;
    const f16*   A    = z == 0 ? Qf  : z == 1 ? Kf  : Vf;
    const f16*   Wm   = z == 0 ? Wqh : z == 1 ? Wkh : Wvh;
    const float* bias = z == 0 ? bq  : z == 1 ? bk  : bv;

    const int m0 = blockIdx.y * 128, n0 = blockIdx.x * 128;
    f32x4 acc[4][4];
    gemm128_core(A, Wm, m0, n0, acc);

    const int t = threadIdx.x, lane = t & 63, w = t >> 6;
    const int quad = lane >> 4, l15 = lane & 15;
    const int wr = w >> 1, wc = w & 1;

    if (z < 2) {
        f16* Out = z == 0 ? Qh : Kh;
#pragma unroll
        for (int j = 0; j < 4; ++j) {
            const int col = n0 + wc * 64 + j * 16 + l15;
            const float bc = bias[col];
#pragma unroll
            for (int i = 0; i < 4; ++i)
#pragma unroll
                for (int r = 0; r < 4; ++r) {
                    const int row = m0 + wr * 64 + i * 16 + quad * 4 + r;
                    Out[(size_t)row * D_MODEL + col] = (f16)(acc[i][j][r] + bc);
                }
        }
    } else {
        // V transposed: Vt[(b*16+h)*64 + d][s]
#pragma unroll
        for (int j = 0; j < 4; ++j) {
            const int col = n0 + wc * 64 + j * 16 + l15;
            const float bc = bias[col];
            const int h = col >> 6, d = col & 63;
#pragma unroll
            for (int i = 0; i < 4; ++i)
#pragma unroll
                for (int r = 0; r < 4; ++r) {
                    const int row = m0 + wr * 64 + i * 16 + quad * 4 + r;
                    const int bb = row >> 11, s = row & (SEQ - 1);
                    Vt[(size_t)((bb * NHEADS + h) * DK + d) * SEQ + s] = (f16)(acc[i][j][r] + bc);
                }
        }
    }
}

// Output projection: fp16 in, fp32 out. grid (8, 32).
__global__ __launch_bounds__(256, 3) void oproj_gemm(
    const f16* __restrict__ A, const f16* __restrict__ Wm,
    const float* __restrict__ bias, float* __restrict__ Out)
{
    const int m0 = blockIdx.y * 128, n0 = blockIdx.x * 128;
    f32x4 acc[4][4];
    gemm128_core(A, Wm, m0, n0, acc);

    const int t = threadIdx.x, lane = t & 63, w = t >> 6;
    const int quad = lane >> 4, l15 = lane & 15;
    const int wr = w >> 1, wc = w & 1;
#pragma unroll
    for (int j = 0; j < 4; ++j) {
        const int col = n0 + wc * 64 + j * 16 + l15;
        const float bc = bias[col];
#pragma unroll
        for (int i = 0; i < 4; ++i)
#pragma unroll
            for (int r = 0; r < 4; ++r) {
                const int row = m0 + wr * 64 + i * 16 + quad * 4 + r;
                Out[(size_t)row * D_MODEL + col] = acc[i][j][r] + bc;
            }
    }
}

// ---------------------------------------------------------------------------
// MFMA fp16 flash attention (validated round 2); epilogue now writes fp16.
// ---------------------------------------------------------------------------
__global__ __launch_bounds__(256) void mha_mfma_f16(
    const f16* __restrict__ Qh, const f16* __restrict__ Kh,
    const f16* __restrict__ Vt, f16* __restrict__ Og)
{
    __shared__ __align__(16) f16 Qs[64][72];
    __shared__ __align__(16) f16 Ks[64][72];
    __shared__ __align__(16) f16 Vs[64][72];
    __shared__ __align__(16) f16 Ps[64][72];

    const int t    = threadIdx.x;
    const int w    = t >> 6;
    const int lane = t & 63;
    const int quad = lane >> 4;
    const int l15  = lane & 15;

    const int qt = blockIdx.x;
    const int bh = blockIdx.y;
    const int b  = bh >> 4;
    const int h  = bh & 15;
    const int q0 = qt * 64;

    const int r0 = t >> 3;
    const int c0 = (t & 7) * 8;

#pragma unroll
    for (int i = 0; i < 2; ++i) {
        int r = r0 + i * 32;
        *(f16x8*)&Qs[r][c0] =
            *(const f16x8*)&Qh[(size_t)(b * SEQ + q0 + r) * D_MODEL + h * DK + c0];
    }
    __syncthreads();

    const f16x8 aQ0 = *(const f16x8*)&Qs[w * 16 + l15][quad * 8];
    const f16x8 aQ1 = *(const f16x8*)&Qs[w * 16 + l15][32 + quad * 8];

    f32x4 o[4];
#pragma unroll
    for (int f = 0; f < 4; ++f) o[f] = (f32x4){0.f, 0.f, 0.f, 0.f};
    float m_run[4], l_run[4];
#pragma unroll
    for (int r = 0; r < 4; ++r) { m_run[r] = -1e30f; l_run[r] = 0.f; }

    for (int kt = 0; kt < SEQ / 64; ++kt) {
        const int kv0 = kt * 64;
#pragma unroll
        for (int i = 0; i < 2; ++i) {
            int r = r0 + i * 32;
            *(f16x8*)&Ks[r][c0] =
                *(const f16x8*)&Kh[(size_t)(b * SEQ + kv0 + r) * D_MODEL + h * DK + c0];
            *(f16x8*)&Vs[r][c0] =
                *(const f16x8*)&Vt[(size_t)(bh * DK + r) * SEQ + kv0 + c0];
        }
        __syncthreads();

        f32x4 s[4];
#pragma unroll
        for (int f = 0; f < 4; ++f) {
            f16x8 b0 = *(const f16x8*)&Ks[f * 16 + l15][quad * 8];
            f16x8 b1 = *(const f16x8*)&Ks[f * 16 + l15][32 + quad * 8];
            f32x4 a0 = (f32x4){0.f, 0.f, 0.f, 0.f};
            a0 = __builtin_amdgcn_mfma_f32_16x16x32_f16(aQ0, b0, a0, 0, 0, 0);
            a0 = __builtin_amdgcn_mfma_f32_16x16x32_f16(aQ1, b1, a0, 0, 0, 0);
            s[f] = a0;
        }

#pragma unroll
        for (int f = 0; f < 4; ++f)
#pragma unroll
            for (int r = 0; r < 4; ++r) s[f][r] *= 0.125f;

#pragma unroll
        for (int r = 0; r < 4; ++r) {
            float v = fmaxf(fmaxf(s[0][r], s[1][r]), fmaxf(s[2][r], s[3][r]));
            v = fmaxf(v, __shfl_xor(v, 1));
            v = fmaxf(v, __shfl_xor(v, 2));
            v = fmaxf(v, __shfl_xor(v, 4));
            v = fmaxf(v, __shfl_xor(v, 8));
            float mn    = fmaxf(m_run[r], v);
            float alpha = __expf(m_run[r] - mn);
            m_run[r] = mn;
            float rsum = 0.f;
#pragma unroll
            for (int f = 0; f < 4; ++f) {
                float p = __expf(s[f][r] - mn);
                s[f][r] = p;
                rsum += p;
            }
            rsum += __shfl_xor(rsum, 1);
            rsum += __shfl_xor(rsum, 2);
            rsum += __shfl_xor(rsum, 4);
            rsum += __shfl_xor(rsum, 8);
            l_run[r] = l_run[r] * alpha + rsum;
#pragma unroll
            for (int f = 0; f < 4; ++f) o[f][r] *= alpha;
        }

#pragma unroll
        for (int f = 0; f < 4; ++f)
#pragma unroll
            for (int r = 0; r < 4; ++r)
                Ps[w * 16 + quad * 4 + r][f * 16 + l15] = (f16)s[f][r];

        f16x8 aP0 = *(const f16x8*)&Ps[w * 16 + l15][quad * 8];
        f16x8 aP1 = *(const f16x8*)&Ps[w * 16 + l15][32 + quad * 8];
#pragma unroll
        for (int f = 0; f < 4; ++f) {
            f16x8 b0 = *(const f16x8*)&Vs[f * 16 + l15][quad * 8];
            f16x8 b1 = *(const f16x8*)&Vs[f * 16 + l15][32 + quad * 8];
            o[f] = __builtin_amdgcn_mfma_f32_16x16x32_f16(aP0, b0, o[f], 0, 0, 0);
            o[f] = __builtin_amdgcn_mfma_f32_16x16x32_f16(aP1, b1, o[f], 0, 0, 0);
        }
        __syncthreads();
    }

#pragma unroll
    for (int r = 0; r < 4; ++r) {
        const float inv = 1.f / l_run[r];
        const size_t row = (size_t)(b * SEQ + q0 + w * 16 + quad * 4 + r) * D_MODEL + h * DK;
#pragma unroll
        for (int f = 0; f < 4; ++f)
            Og[row + f * 16 + l15] = (f16)(o[f][r] * inv);
    }
}

// ---------------------------------------------------------------------------
extern "C" void kernel_launch(void* const* d_in, const int* in_sizes, int n_in,
                              void* d_out, int out_size, void* d_ws, size_t ws_size,
                              hipStream_t stream)
{
    const float* query = (const float*)d_in[0];
    const float* key   = (const float*)d_in[1];
    const float* value = (const float*)d_in[2];
    const float* Wq    = (const float*)d_in[3];
    const float* bq    = (const float*)d_in[4];
    const float* Wk    = (const float*)d_in[5];
    const float* bk    = (const float*)d_in[6];
    const float* Wv    = (const float*)d_in[7];
    const float* bv    = (const float*)d_in[8];
    const float* Wo    = (const float*)d_in[9];
    const float* bo    = (const float*)d_in[10];
    float* out = (float*)d_out;

    // ws layout (f16 elems): Qf Kf Vf (4M ea) | Wqh Wkh Wvh Woh (1M ea) |
    //                        Qh Kh Vt ATh (4M ea)   => 32M f16 = 64 MB
    f16* Qf  = (f16*)d_ws;
    f16* Kf  = Qf  + (size_t)MTOT * D_MODEL;
    f16* Vf  = Kf  + (size_t)MTOT * D_MODEL;
    f16* Wqh = Vf  + (size_t)MTOT * D_MODEL;
    f16* Wkh = Wqh + (size_t)D_MODEL * D_MODEL;
    f16* Wvh = Wkh + (size_t)D_MODEL * D_MODEL;
    f16* Woh = Wvh + (size_t)D_MODEL * D_MODEL;
    f16* Qh  = Woh + (size_t)D_MODEL * D_MODEL;
    f16* Kh  = Qh  + (size_t)MTOT * D_MODEL;
    f16* Vt  = Kh  + (size_t)MTOT * D_MODEL;
    f16* ATh = Vt  + (size_t)MTOT * D_MODEL;

    cvt_f32_to_f16<<<dim3(1024, 7), 256, 0, stream>>>(
        query, key, value, Wq, Wk, Wv, Wo, Qf, Kf, Vf, Wqh, Wkh, Wvh, Woh);

    qkv_gemm<<<dim3(D_MODEL / 128, MTOT / 128, 3), 256, 0, stream>>>(
        Qf, Kf, Vf, Wqh, Wkh, Wvh, bq, bk, bv, Qh, Kh, Vt);

    mha_mfma_f16<<<dim3(SEQ / 64, NBATCH * NHEADS), 256, 0, stream>>>(Qh, Kh, Vt, ATh);

    oproj_gemm<<<dim3(D_MODEL / 128, MTOT / 128), 256, 0, stream>>>(ATh, Woh, bo, out);
}

// Round 4
// 289.222 us; speedup vs baseline: 6.3538x; 1.1349x over previous
//
#include <hip/hip_runtime.h>

#define D_MODEL 1024
#define NHEADS  16
#define DK      64
#define SEQ     2048
#define NBATCH  2
#define MTOT    (NBATCH * SEQ)   // 4096 rows

typedef _Float16 f16;
typedef _Float16 f16x4 __attribute__((ext_vector_type(4)));
typedef _Float16 f16x8 __attribute__((ext_vector_type(8)));
typedef float    f32x4 __attribute__((ext_vector_type(4)));

// ---------------------------------------------------------------------------
// fp32 -> fp16 convert (inputs + weights), one batched launch.
// ---------------------------------------------------------------------------
__global__ __launch_bounds__(256) void cvt_f32_to_f16(
    const float* __restrict__ q, const float* __restrict__ k, const float* __restrict__ v,
    const float* __restrict__ wq, const float* __restrict__ wk,
    const float* __restrict__ wv, const float* __restrict__ wo,
    f16* __restrict__ qf, f16* __restrict__ kf, f16* __restrict__ vf,
    f16* __restrict__ wqh, f16* __restrict__ wkh, f16* __restrict__ wvh, f16* __restrict__ woh)
{
    const int z = blockIdx.y;
    const float* src; f16* dst; int n4;
    if (z == 0)      { src = q;  dst = qf;  n4 = MTOT * D_MODEL / 4; }
    else if (z == 1) { src = k;  dst = kf;  n4 = MTOT * D_MODEL / 4; }
    else if (z == 2) { src = v;  dst = vf;  n4 = MTOT * D_MODEL / 4; }
    else if (z == 3) { src = wq; dst = wqh; n4 = D_MODEL * D_MODEL / 4; }
    else if (z == 4) { src = wk; dst = wkh; n4 = D_MODEL * D_MODEL / 4; }
    else if (z == 5) { src = wv; dst = wvh; n4 = D_MODEL * D_MODEL / 4; }
    else             { src = wo; dst = woh; n4 = D_MODEL * D_MODEL / 4; }
    for (int i = blockIdx.x * 256 + threadIdx.x; i < n4; i += gridDim.x * 256) {
        float4 t = ((const float4*)src)[i];
        f16x4 o = {(f16)t.x, (f16)t.y, (f16)t.z, (f16)t.w};
        ((f16x4*)dst)[i] = o;
    }
}

// ---------------------------------------------------------------------------
// m97-style fp16 MFMA GEMM core (validated round 3).
// ---------------------------------------------------------------------------
__device__ __forceinline__ void gemm128_core(
    const f16* __restrict__ A, const f16* __restrict__ Wm,
    int m0, int n0, f32x4 (&acc)[4][4])
{
    __shared__ __align__(16) f16 As[4096];
    __shared__ __align__(16) f16 Bs[4096];

    const int t    = threadIdx.x;
    const int lane = t & 63;
    const int w    = t >> 6;
    const int quad = lane >> 4, l15 = lane & 15;
    const int wr   = w >> 1,    wc  = w & 1;

    size_t offA[2], offB[2];
#pragma unroll
    for (int jj = 0; jj < 2; ++jj) {
        int s  = (w * 2 + jj) * 64 + lane;   // slot = ko*128 + m
        int ko = s >> 7, m = s & 127;
        offA[jj] = (size_t)(m0 + m) * D_MODEL + ko * 8;
        offB[jj] = (size_t)(n0 + m) * D_MODEL + ko * 8;
    }
    const int jb = __builtin_amdgcn_readfirstlane(w * 2 * 512);

#pragma unroll
    for (int i = 0; i < 4; ++i)
#pragma unroll
        for (int j = 0; j < 4; ++j) acc[i][j] = (f32x4){0.f, 0.f, 0.f, 0.f};

    auto* ldsA = (__attribute__((address_space(3))) f16*)As;
    auto* ldsB = (__attribute__((address_space(3))) f16*)Bs;

    for (int k0 = 0; k0 < D_MODEL; k0 += 32) {
#pragma unroll
        for (int jj = 0; jj < 2; ++jj) {
            __builtin_amdgcn_global_load_lds(
                (const __attribute__((address_space(1))) void*)(A + offA[jj] + k0),
                (__attribute__((address_space(3))) void*)(ldsA + jb + jj * 512),
                16, 0, 0);
            __builtin_amdgcn_global_load_lds(
                (const __attribute__((address_space(1))) void*)(Wm + offB[jj] + k0),
                (__attribute__((address_space(3))) void*)(ldsB + jb + jj * 512),
                16, 0, 0);
        }
        __syncthreads();

        f16x8 af[4], bf[4];
#pragma unroll
        for (int i = 0; i < 4; ++i) {
            af[i] = *(const f16x8*)&As[quad * 1024 + (wr * 64 + i * 16 + l15) * 8];
            bf[i] = *(const f16x8*)&Bs[quad * 1024 + (wc * 64 + i * 16 + l15) * 8];
        }
#pragma unroll
        for (int i = 0; i < 4; ++i)
#pragma unroll
            for (int j = 0; j < 4; ++j)
                acc[i][j] = __builtin_amdgcn_mfma_f32_16x16x32_f16(af[i], bf[j], acc[i][j], 0, 0, 0);
        __syncthreads();
    }
}

// Fused Q/K/V projection. Q output pre-scaled by 1/sqrt(dk)=0.125.
__global__ __launch_bounds__(256, 3) void qkv_gemm(
    const f16* __restrict__ Qf, const f16* __restrict__ Kf, const f16* __restrict__ Vf,
    const f16* __restrict__ Wqh, const f16* __restrict__ Wkh, const f16* __restrict__ Wvh,
    const float* __restrict__ bq, const float* __restrict__ bk, const float* __restrict__ bv,
    f16* __restrict__ Qh, f16* __restrict__ Kh, f16* __restrict__ Vt)
{
    const int z = blockIdx.z;
    const f16*   A    = z == 0 ? Qf  : z == 1 ? Kf  : Vf;
    const f16*   Wm   = z == 0 ? Wqh : z == 1 ? Wkh : Wvh;
    const float* bias = z == 0 ? bq  : z == 1 ? bk  : bv;

    const int m0 = blockIdx.y * 128, n0 = blockIdx.x * 128;
    f32x4 acc[4][4];
    gemm128_core(A, Wm, m0, n0, acc);

    const int t = threadIdx.x, lane = t & 63, w = t >> 6;
    const int quad = lane >> 4, l15 = lane & 15;
    const int wr = w >> 1, wc = w & 1;

    if (z < 2) {
        f16* Out = z == 0 ? Qh : Kh;
        const float sc = z == 0 ? 0.125f : 1.0f;
#pragma unroll
        for (int j = 0; j < 4; ++j) {
            const int col = n0 + wc * 64 + j * 16 + l15;
            const float bc = bias[col];
#pragma unroll
            for (int i = 0; i < 4; ++i)
#pragma unroll
                for (int r = 0; r < 4; ++r) {
                    const int row = m0 + wr * 64 + i * 16 + quad * 4 + r;
                    Out[(size_t)row * D_MODEL + col] = (f16)((acc[i][j][r] + bc) * sc);
                }
        }
    } else {
        // V transposed: Vt[(b*16+h)*64 + d][s]
#pragma unroll
        for (int j = 0; j < 4; ++j) {
            const int col = n0 + wc * 64 + j * 16 + l15;
            const float bc = bias[col];
            const int h = col >> 6, d = col & 63;
#pragma unroll
            for (int i = 0; i < 4; ++i)
#pragma unroll
                for (int r = 0; r < 4; ++r) {
                    const int row = m0 + wr * 64 + i * 16 + quad * 4 + r;
                    const int bb = row >> 11, s = row & (SEQ - 1);
                    Vt[(size_t)((bb * NHEADS + h) * DK + d) * SEQ + s] = (f16)(acc[i][j][r] + bc);
                }
        }
    }
}

// Output projection: fp16 in, fp32 out.
__global__ __launch_bounds__(256, 3) void oproj_gemm(
    const f16* __restrict__ A, const f16* __restrict__ Wm,
    const float* __restrict__ bias, float* __restrict__ Out)
{
    const int m0 = blockIdx.y * 128, n0 = blockIdx.x * 128;
    f32x4 acc[4][4];
    gemm128_core(A, Wm, m0, n0, acc);

    const int t = threadIdx.x, lane = t & 63, w = t >> 6;
    const int quad = lane >> 4, l15 = lane & 15;
    const int wr = w >> 1, wc = w & 1;
#pragma unroll
    for (int j = 0; j < 4; ++j) {
        const int col = n0 + wc * 64 + j * 16 + l15;
        const float bc = bias[col];
#pragma unroll
        for (int i = 0; i < 4; ++i)
#pragma unroll
            for (int r = 0; r < 4; ++r) {
                const int row = m0 + wr * 64 + i * 16 + quad * 4 + r;
                Out[(size_t)row * D_MODEL + col] = acc[i][j][r] + bc;
            }
    }
}

// ---------------------------------------------------------------------------
// 16-lane max reduction on the VALU pipe (DPP), no LDS ops.
// Steps: xor1 (quad_perm 0xB1), xor2 (quad_perm 0x4E), cross-quad within 8
// (row_half_mirror 0x141), cross-8 within 16 (row_mirror 0x140).
// ---------------------------------------------------------------------------
__device__ __forceinline__ float dpp_max16(float v) {
    v = fmaxf(v, __uint_as_float(__builtin_amdgcn_update_dpp(
            0, (int)__float_as_uint(v), 0xB1, 0xF, 0xF, false)));
    v = fmaxf(v, __uint_as_float(__builtin_amdgcn_update_dpp(
            0, (int)__float_as_uint(v), 0x4E, 0xF, 0xF, false)));
    v = fmaxf(v, __uint_as_float(__builtin_amdgcn_update_dpp(
            0, (int)__float_as_uint(v), 0x141, 0xF, 0xF, false)));
    v = fmaxf(v, __uint_as_float(__builtin_amdgcn_update_dpp(
            0, (int)__float_as_uint(v), 0x140, 0xF, 0xF, false)));
    return v;
}

// ---------------------------------------------------------------------------
// Flash attention v3. Block = 128 q-rows x (b,h); 4 waves, wave owns 32 q
// (2 strips of 16). K-tile = 64 keys. Q entirely in registers (global load,
// pre-scaled). K/V staged via global_load_lds (chunked: slot = ko*64 + row).
// Softmax: row-max via DPP (VALU pipe), row-sum via ones-column MFMA.
// P round-trip through LDS rows padded to 68 f16 (conflict-free b16 scatter).
// LDS: 8 + 8 + 17 KB = 33 KB. Grid 16 x 32 = 512 blocks = 2/CU.
// ---------------------------------------------------------------------------
__global__ __launch_bounds__(256, 2) void mha_mfma_v3(
    const f16* __restrict__ Qh, const f16* __restrict__ Kh,
    const f16* __restrict__ Vt, f16* __restrict__ Og)
{
    __shared__ __align__(16) f16 Ks[4096];
    __shared__ __align__(16) f16 Vc[4096];
    __shared__ __align__(16) f16 Ps[128 * 68];

    const int t    = threadIdx.x;
    const int w    = t >> 6;
    const int lane = t & 63;
    const int quad = lane >> 4, l15 = lane & 15;

    const int qt = blockIdx.x, bh = blockIdx.y;
    const int b  = bh >> 4,    h  = bh & 15;
    const int q0 = qt * 128;

    // ---- Q A-frags from global (one-time; Qh pre-scaled by 0.125) ----
    f16x8 aQ[2][2];
#pragma unroll
    for (int s = 0; s < 2; ++s)
#pragma unroll
        for (int c = 0; c < 2; ++c)
            aQ[s][c] = *(const f16x8*)&Qh[
                (size_t)(b * SEQ + q0 + w * 32 + s * 16 + l15) * D_MODEL
                + h * DK + c * 32 + quad * 8];

    // ---- staging pointers: wave w deposits chunks 2w, 2w+1 ----
    const f16* gK[2]; const f16* gV[2]; int ldst[2];
#pragma unroll
    for (int jj = 0; jj < 2; ++jj) {
        const int kc = w * 2 + jj;            // 0..7
        gK[jj] = Kh + (size_t)(b * SEQ + lane) * D_MODEL + h * DK + kc * 8;
        gV[jj] = Vt + (size_t)(bh * DK + lane) * SEQ + kc * 8;
        ldst[jj] = __builtin_amdgcn_readfirstlane(kc * 512);   // f16 offset
    }
    auto* ldsK = (__attribute__((address_space(3))) f16*)Ks;
    auto* ldsV = (__attribute__((address_space(3))) f16*)Vc;

    const f16x8 onesB = {(f16)1.f, (f16)1.f, (f16)1.f, (f16)1.f,
                         (f16)1.f, (f16)1.f, (f16)1.f, (f16)1.f};

    f32x4 o[2][4];
#pragma unroll
    for (int s = 0; s < 2; ++s)
#pragma unroll
        for (int j = 0; j < 4; ++j) o[s][j] = (f32x4){0.f, 0.f, 0.f, 0.f};
    f32x4 sacc[2] = {(f32x4){0.f, 0.f, 0.f, 0.f}, (f32x4){0.f, 0.f, 0.f, 0.f}};
    float m_run[2][4];
#pragma unroll
    for (int s = 0; s < 2; ++s)
#pragma unroll
        for (int r = 0; r < 4; ++r) m_run[s][r] = -1e30f;

    for (int kt = 0; kt < SEQ / 64; ++kt) {
        // ---- stage K,V tiles (4 DMA instrs per wave) ----
#pragma unroll
        for (int jj = 0; jj < 2; ++jj) {
            __builtin_amdgcn_global_load_lds(
                (const __attribute__((address_space(1))) void*)(gK[jj] + (size_t)kt * 64 * D_MODEL),
                (__attribute__((address_space(3))) void*)(ldsK + ldst[jj]), 16, 0, 0);
            __builtin_amdgcn_global_load_lds(
                (const __attribute__((address_space(1))) void*)(gV[jj] + kt * 64),
                (__attribute__((address_space(3))) void*)(ldsV + ldst[jj]), 16, 0, 0);
        }
        __syncthreads();

        // ---- K/V B-frags ----
        f16x8 bK[4][2], bV[4][2];
#pragma unroll
        for (int f = 0; f < 4; ++f)
#pragma unroll
            for (int c = 0; c < 2; ++c) {
                const int slot = ((c * 4 + quad) * 64 + f * 16 + l15) * 8;
                bK[f][c] = *(const f16x8*)&Ks[slot];
                bV[f][c] = *(const f16x8*)&Vc[slot];
            }

#pragma unroll
        for (int s = 0; s < 2; ++s) {
            // ---- S strip (16 q x 64 keys) ----
            f32x4 sc[4];
#pragma unroll
            for (int f = 0; f < 4; ++f) {
                f32x4 a = (f32x4){0.f, 0.f, 0.f, 0.f};
                a = __builtin_amdgcn_mfma_f32_16x16x32_f16(aQ[s][0], bK[f][0], a, 0, 0, 0);
                a = __builtin_amdgcn_mfma_f32_16x16x32_f16(aQ[s][1], bK[f][1], a, 0, 0, 0);
                sc[f] = a;
            }

            // ---- online softmax: DPP max, ones-MFMA sum ----
            float al[4];
#pragma unroll
            for (int r = 0; r < 4; ++r) {
                float mt = fmaxf(fmaxf(sc[0][r], sc[1][r]), fmaxf(sc[2][r], sc[3][r]));
                mt = dpp_max16(mt);
                const float mn = fmaxf(m_run[s][r], mt);
                al[r] = __expf(m_run[s][r] - mn);
                m_run[s][r] = mn;
#pragma unroll
                for (int f = 0; f < 4; ++f) sc[f][r] = __expf(sc[f][r] - mn);
                sacc[s][r] *= al[r];
#pragma unroll
                for (int j = 0; j < 4; ++j) o[s][j][r] *= al[r];
            }

            // ---- P -> LDS (C-layout write, conflict-free), A-layout readback ----
#pragma unroll
            for (int f = 0; f < 4; ++f)
#pragma unroll
                for (int r = 0; r < 4; ++r)
                    Ps[(w * 32 + s * 16 + quad * 4 + r) * 68 + f * 16 + l15] = (f16)sc[f][r];

            f16x8 aP[2];
#pragma unroll
            for (int c = 0; c < 2; ++c) {
                const int off = (w * 32 + s * 16 + l15) * 68 + c * 32 + quad * 8;
                f16x4 lo = *(const f16x4*)&Ps[off];
                f16x4 hi = *(const f16x4*)&Ps[off + 4];
                aP[c] = __builtin_shufflevector(lo, hi, 0, 1, 2, 3, 4, 5, 6, 7);
            }

            // ---- O += P V ; l += row-sum(P) via ones column ----
#pragma unroll
            for (int j = 0; j < 4; ++j) {
                o[s][j] = __builtin_amdgcn_mfma_f32_16x16x32_f16(aP[0], bV[j][0], o[s][j], 0, 0, 0);
                o[s][j] = __builtin_amdgcn_mfma_f32_16x16x32_f16(aP[1], bV[j][1], o[s][j], 0, 0, 0);
            }
            sacc[s] = __builtin_amdgcn_mfma_f32_16x16x32_f16(aP[0], onesB, sacc[s], 0, 0, 0);
            sacc[s] = __builtin_amdgcn_mfma_f32_16x16x32_f16(aP[1], onesB, sacc[s], 0, 0, 0);
        }
        __syncthreads();   // K/V consumed before next-iter staging
    }

    // ---- epilogue ----
#pragma unroll
    for (int s = 0; s < 2; ++s)
#pragma unroll
        for (int r = 0; r < 4; ++r) {
            const float inv = 1.f / sacc[s][r];
            const size_t row = (size_t)(b * SEQ + q0 + w * 32 + s * 16 + quad * 4 + r) * D_MODEL
                               + h * DK;
#pragma unroll
            for (int j = 0; j < 4; ++j)
                Og[row + j * 16 + l15] = (f16)(o[s][j][r] * inv);
        }
}

// ---------------------------------------------------------------------------
extern "C" void kernel_launch(void* const* d_in, const int* in_sizes, int n_in,
                              void* d_out, int out_size, void* d_ws, size_t ws_size,
                              hipStream_t stream)
{
    const float* query = (const float*)d_in[0];
    const float* key   = (const float*)d_in[1];
    const float* value = (const float*)d_in[2];
    const float* Wq    = (const float*)d_in[3];
    const float* bq    = (const float*)d_in[4];
    const float* Wk    = (const float*)d_in[5];
    const float* bk    = (const float*)d_in[6];
    const float* Wv    = (const float*)d_in[7];
    const float* bv    = (const float*)d_in[8];
    const float* Wo    = (const float*)d_in[9];
    const float* bo    = (const float*)d_in[10];
    float* out = (float*)d_out;

    f16* Qf  = (f16*)d_ws;
    f16* Kf  = Qf  + (size_t)MTOT * D_MODEL;
    f16* Vf  = Kf  + (size_t)MTOT * D_MODEL;
    f16* Wqh = Vf  + (size_t)MTOT * D_MODEL;
    f16* Wkh = Wqh + (size_t)D_MODEL * D_MODEL;
    f16* Wvh = Wkh + (size_t)D_MODEL * D_MODEL;
    f16* Woh = Wvh + (size_t)D_MODEL * D_MODEL;
    f16* Qh  = Woh + (size_t)D_MODEL * D_MODEL;
    f16* Kh  = Qh  + (size_t)MTOT * D_MODEL;
    f16* Vt  = Kh  + (size_t)MTOT * D_MODEL;
    f16* ATh = Vt  + (size_t)MTOT * D_MODEL;

    cvt_f32_to_f16<<<dim3(1024, 7), 256, 0, stream>>>(
        query, key, value, Wq, Wk, Wv, Wo, Qf, Kf, Vf, Wqh, Wkh, Wvh, Woh);

    qkv_gemm<<<dim3(D_MODEL / 128, MTOT / 128, 3), 256, 0, stream>>>(
        Qf, Kf, Vf, Wqh, Wkh, Wvh, bq, bk, bv, Qh, Kh, Vt);

    mha_mfma_v3<<<dim3(SEQ / 128, NBATCH * NHEADS), 256, 0, stream>>>(Qh, Kh, Vt, ATh);

    oproj_gemm<<<dim3(D_MODEL / 128, MTOT / 128), 256, 0, stream>>>(ATh, Woh, bo, out);
}